// Round 11
// baseline (49.091 us; speedup 1.0000x reference)
//
#include <hip/hip_runtime.h>

#define T_DIM 512
#define B_DIM 64
#define V_DIM 1296
#define S_DIM 30
#define LN2   0.6931471805599453f

typedef float v2f __attribute__((ext_vector_type(2)));

// DPP helper. bound_ctrl=true -> lanes with no source read 0.
template<int CTRL, bool BC>
__device__ __forceinline__ float dppf(float src, float old) {
    return __int_as_float(__builtin_amdgcn_update_dpp(
        __float_as_int(old), __float_as_int(src), CTRL, 0xF, 0xF, BC));
}

// ---------------------------------------------------------------------------
// Kernel 1 (verbatim round 8): gather. 256 blocks (b = bid>>2, quarter =
// bid&3), 512 threads. Each thread: up to 12 independent scattered loads
// issued as one burst -> exp -> 4 coalesced float4 stores into
// compact[b][t][slot]. All 256 CUs active, 8 waves/CU. Zeroes K2's counter.
// ---------------------------------------------------------------------------
__global__ __launch_bounds__(512)
void ctc_gather_kernel(const float* __restrict__ log_probs,
                       const int*   __restrict__ targets,
                       const int*   __restrict__ input_lengths,
                       float4*      __restrict__ compact,   // (B,T,16)
                       unsigned*    __restrict__ counter)
{
    const int bid = blockIdx.x;
    const int b   = bid >> 2;
    const int qt  = bid & 3;
    const int tid = threadIdx.x;
    const int s   = tid & 15;          // lattice slot 0..15
    const int ri  = tid >> 4;          // row offset 0..31
    const int len = input_lengths[b];
    if (bid == 0 && tid == 0) *counter = 0u;

    int lab0 = 0, lab1 = 0;
    if (s < 15) {
        lab0 = targets[b * S_DIM + 2 * s];
        lab1 = targets[b * S_DIM + 2 * s + 1];
    }
    const float* lpb = log_probs + (size_t)b * V_DIM;

    float va[4], vb[4], vc[4];
    int   trow[4];
    bool  act[4];
#pragma unroll
    for (int k = 0; k < 4; ++k) {      // issue all loads first (MLP)
        int t = qt * 128 + k * 32 + ri;
        trow[k] = t;
        act[k]  = (t < len);
        if (act[k]) {
            const float* row = lpb + (size_t)t * (B_DIM * V_DIM);
            va[k] = row[lab0];
            vb[k] = row[lab1];
            vc[k] = row[0];
        }
    }
#pragma unroll
    for (int k = 0; k < 4; ++k) {
        if (act[k]) {
            float wb = __expf(vc[k]);
            float w0 = (s < 15) ? __expf(va[k]) : 0.f;   // lane15 labels absent
            float w1 = (s < 15) ? __expf(vb[k]) : 0.f;
            compact[((size_t)b * T_DIM + trow[k]) * 16 + s] =
                make_float4(w0, w1, wb, wb);
        }
    }
}

// ---------------------------------------------------------------------------
// One 32-step chunk of the quad-packed scaled CTC recursion (verbatim round
// 9), reading straight from global compact with a 32-deep register pipeline.
// Lane l (0..15): X=(alpha[4l],alpha[4l+2]) blanks, Y=(alpha[4l+1],alpha[4l+3])
// labels, scaled by 2^E. MODE 0: chunk 0 (t=0 init). MODE 1: full. MODE 2: pred.
// ---------------------------------------------------------------------------
template<int MODE>
__device__ __forceinline__ void scan_chunk32(const float4* __restrict__ gp,
                                             float4 (&buf)[32], int c, int len,
                                             int lane, v2f S, v2f& X, v2f& Y,
                                             int& E)
{
    float mred = 0.f;
#pragma unroll
    for (int ii = 0; ii < 32; ++ii) {
        float4 w = buf[ii];
        if (c < 15) buf[ii] = gp[(size_t)((c + 1) * 32 + ii) * 16];  // refill +32

        if (MODE == 0 && ii == 0) {
            bool l0 = (lane == 0);
            X = (v2f){ l0 ? ldexpf(w.z, 64) : 0.f, 0.f };   // alpha[0] = w_blank
            Y = (v2f){ l0 ? ldexpf(w.x, 64) : 0.f, 0.f };   // alpha[1] = w_lab0
            E = 64;
        } else {
            float q3m = dppf<0x111, true>(Y.y, 0.f);        // alpha[4l-1] from l-1
            v2f Z  = { q3m, Y.x };
            v2f T1 = X + Z;
            v2f T2 = X + Y;
            v2f T3 = __builtin_elementwise_fma(S, Z, T2);   // + skip terms
            v2f Wb = { w.z, w.w };
            v2f Wl = { w.x, w.y };
            v2f Xn = T1 * Wb;
            v2f Yn = T3 * Wl;
            if (MODE == 2) {
                bool act = (c * 32 + ii) < len;
                X = act ? Xn : X;
                Y = act ? Yn : Y;
            } else { X = Xn; Y = Yn; }
        }

        // renorm window of 8: stale snapshot at 3, reduce 4..6 (off-chain),
        // exact power-of-2 rescale at 7.
        if ((ii & 7) == 3) mred = fmaxf(fmaxf(X.x, X.y), fmaxf(Y.x, Y.y));
        if ((ii & 7) == 4) mred = fmaxf(mred, dppf<0x111, true>(mred, 0.f));
        if ((ii & 7) == 5) mred = fmaxf(mred, dppf<0x112, true>(mred, 0.f));
        if ((ii & 7) == 6) mred = fmaxf(mred, dppf<0x114, true>(mred, 0.f));
        if ((ii & 7) == 7) {
            mred = fmaxf(mred, dppf<0x118, true>(mred, 0.f)); // lane15=max(0..15)
            int e15 = (__builtin_amdgcn_readlane(__float_as_int(mred), 15) >> 23) & 0xFF;
            int sfx = 191 - e15;                              // recenter at 2^64
            X = (v2f){ ldexpf(X.x, sfx), ldexpf(X.y, sfx) };
            Y = (v2f){ ldexpf(Y.x, sfx), ldexpf(Y.y, sfx) };
            E += sfx;
        }
    }
}

// ---------------------------------------------------------------------------
// Kernel 2 (verbatim round 9): scan. 64 blocks x 1 wave, no LDS, no barriers.
// Reads compact (L2/L3-resident after K1) with 32 float4 loads in flight.
// ---------------------------------------------------------------------------
__global__ __launch_bounds__(64)
void ctc_scan_kernel(const float4* __restrict__ compact,
                     const int*    __restrict__ targets,
                     const int*    __restrict__ input_lengths,
                     const int*    __restrict__ target_lengths,
                     float*        __restrict__ losses,
                     unsigned*     __restrict__ counter,
                     float*        __restrict__ out)
{
    const int b    = blockIdx.x;
    const int lane = threadIdx.x;
    const int jl   = lane & 15;
    const int len  = input_lengths[b];
    const int tl   = target_lengths[b];

    float s0 = 0.f, s1 = 0.f;
    if (jl < 15) {
        int k0 = 2 * jl;
        int tc = targets[b * S_DIM + k0];
        int tp = (k0 > 0) ? targets[b * S_DIM + k0 - 1] : -1;  // -1 = blank
        s0 = (tc != tp) ? 1.f : 0.f;
        int tn = targets[b * S_DIM + k0 + 1];
        s1 = (tn != tc) ? 1.f : 0.f;
    }
    v2f S = { s0, s1 };
    v2f X = { 0.f, 0.f }, Y = { 0.f, 0.f };
    int E = 0;

    const float4* gp = compact + (size_t)b * T_DIM * 16 + jl;
    float4 buf[32];
#pragma unroll
    for (int i = 0; i < 32; ++i) buf[i] = gp[(size_t)i * 16];  // chunk 0 preload

    for (int c = 0; c < 16; ++c) {
        if (c * 32 >= len) break;                   // wave-uniform
        if (c == 0)                   scan_chunk32<0>(gp, buf, c, len, lane, S, X, Y, E);
        else if ((c + 1) * 32 <= len) scan_chunk32<1>(gp, buf, c, len, lane, S, X, Y, E);
        else                          scan_chunk32<2>(gp, buf, c, len, lane, S, X, Y, E);
    }

    // alpha[2*tl] (pos 60: lane15 X.x) and alpha[2*tl-1] (pos 59: lane14 Y.y)
    int pB_p = 2 * tl, pL_p = 2 * tl - 1;
    float vB = (pB_p & 2) ? ((pB_p & 1) ? Y.y : X.y) : ((pB_p & 1) ? Y.x : X.x);
    float vL = (pL_p & 2) ? ((pL_p & 1) ? Y.y : X.y) : ((pL_p & 1) ? Y.x : X.x);
    float pB = __shfl(vB, pB_p >> 2);
    float pL = __shfl(vL, pL_p >> 2);
    float loss = -LN2 * (__builtin_amdgcn_logf(pB + pL) - (float)E);
    if (!(loss < 1e29f)) loss = 0.f;                // zero_infinity (inf/NaN)
    loss /= (float)tl;

    unsigned old = 0;
    if (lane == 0) {
        losses[b] = loss;
        __threadfence();                            // release per-block loss
        old = atomicAdd(counter, 1u);               // device scope
    }
    old = __shfl(old, 0);
    if (old == 63u) {                               // last block reduces
        __threadfence();                            // acquire
        float v = ((volatile const float*)losses)[lane];
#pragma unroll
        for (int off = 32; off >= 1; off >>= 1)
            v += __shfl_xor(v, off);
        if (lane == 0) out[0] = v * (1.f / (float)B_DIM);
    }
}

extern "C" void kernel_launch(void* const* d_in, const int* in_sizes, int n_in,
                              void* d_out, int out_size, void* d_ws, size_t ws_size,
                              hipStream_t stream)
{
    const float* log_probs      = (const float*)d_in[0];
    const int*   targets        = (const int*)  d_in[1];
    const int*   input_lengths  = (const int*)  d_in[2];
    const int*   target_lengths = (const int*)  d_in[3];
    float*       out            = (float*)d_out;

    // ws layout: compact 8 MB | losses (256 B) | counter
    float4*   compact = (float4*)d_ws;
    float*    losses  = (float*)((char*)d_ws + (size_t)8 * 1024 * 1024);
    unsigned* counter = (unsigned*)((char*)d_ws + (size_t)8 * 1024 * 1024 + 256);

    hipLaunchKernelGGL(ctc_gather_kernel, dim3(256), dim3(512), 0, stream,
                       log_probs, targets, input_lengths, compact, counter);
    hipLaunchKernelGGL(ctc_scan_kernel, dim3(B_DIM), dim3(64), 0, stream,
                       compact, targets, input_lengths, target_lengths,
                       losses, counter, out);
}

// Round 12
// 37.753 us; speedup vs baseline: 1.3003x; 1.3003x over previous
//
#include <hip/hip_runtime.h>

#define T_DIM 512
#define B_DIM 64
#define V_DIM 1296
#define S_DIM 30
#define LN2   0.6931471805599453f

// DPP helper (ctrl/masks compile-time). bound_ctrl=true -> lanes with no
// source read 0 (exactly the linear-domain "-inf").
template<int CTRL, bool BC>
__device__ __forceinline__ float dppf(float src, float old) {
    return __int_as_float(__builtin_amdgcn_update_dpp(
        __float_as_int(old), __float_as_int(src), CTRL, 0xF, 0xF, BC));
}

struct ScanSt { float p0, p1; int E; };

// One 32-step chunk of the scaled (linear-domain) CTC forward recursion.
// Lane l holds p0 = alpha[2l] (blank) and p1 = alpha[2l+1] (label l), both
// scaled by 2^E (E wave-uniform). MODE 0: first chunk (t==0 init),
// MODE 1: full, MODE 2: boundary (predicate t < len).  [verbatim round 4]
template<int MODE>
__device__ __forceinline__ void consume_chunk(const float2* __restrict__ ringc,
                                              int c, int len, int jl, bool is16,
                                              float skipw, int l, ScanSt& st)
{
    float p0 = st.p0, p1 = st.p1;
    int   E  = st.E;
    float2 buf[8];
#pragma unroll
    for (int i = 0; i < 8; ++i) buf[i] = ringc[i * 32 + jl];
#pragma unroll
    for (int i = 0; i < 32; ++i) {
        float2 w = buf[i & 7];
        if (i + 8 < 32) buf[i & 7] = ringc[(i + 8) * 32 + jl];
        if (MODE == 0 && i == 0) {
            // t = 0 init: alpha0[0] = w.x, alpha0[1] = w.y (lane 0), scaled 2^64
            p0 = (l == 0) ? ldexpf(w.x, 64) : 0.f;
            p1 = (l == 0) ? ldexpf(w.y, 64) : 0.f;
            E = 64;
        } else {
            float shr = dppf<0x111, true >(p1, 0.f);  // lane l <- l-1 (rows); 0/16/32/48 -> 0
            float bcv = dppf<0x142, false>(p1, p1);   // lanes 16-31 <- lane 15
            float p1m = is16 ? bcv : shr;             // alpha[2l-1]
            float np1 = fmaf(skipw, p1m, p0 + p1) * w.y;  // odd pos 2l+1 (with skip)
            float np0 = (p0 + p1m) * w.x;                 // even pos 2l (no skip)
            if (MODE == 2) {
                bool act = (c * 32 + i) < len;
                p0 = act ? np0 : p0;
                p1 = act ? np1 : p1;
            } else {
                p0 = np0; p1 = np1;
            }
        }
        if ((i & 7) == 7) {
            // renorm every 8 steps: re-center max (lanes 0..31) at 2^64.
            float m = fmaxf(p0, p1);
            m = fmaxf(m, dppf<0x111, true >(m, 0.f));
            m = fmaxf(m, dppf<0x112, true >(m, 0.f));
            m = fmaxf(m, dppf<0x114, true >(m, 0.f));
            m = fmaxf(m, dppf<0x118, true >(m, 0.f));
            m = fmaxf(m, dppf<0x142, false>(m, m));   // lane31 = max(lanes 0..31)
            int eb  = (__float_as_int(m) >> 23) & 0xFF;
            int e31 = __builtin_amdgcn_readlane(eb, 31);
            int s   = 191 - e31;                      // (64+127) - biased exp
            p0 = ldexpf(p0, s);                       // exact power-of-2 scaling
            p1 = ldexpf(p1, s);
            E += s;
        }
    }
    st.p0 = p0; st.p1 = p1; st.E = E;
}

// Producer: stage one 32-row chunk of {w_blank, w_label_j} = exp(lp) into LDS.
// Thread p (0..511) owns entries p and p+512 (fixed j = p&31, rows p>>5, p>>5+16).
__device__ __forceinline__ void stage_chunk(int k, int b, int trow, int lab, int p,
                                            const float* __restrict__ lp,
                                            float2* __restrict__ ring)
{
    int t0 = k * 32 + trow;
    const float* r0 = lp + ((size_t)t0 * B_DIM + b) * V_DIM;
    const float* r1 = r0 + (size_t)16 * B_DIM * V_DIM;   // t0 + 16
    float b0 = r0[0], l0 = r0[lab];
    float b1 = r1[0], l1 = r1[lab];
    float2* slot = ring + (size_t)(k & 3) * 1024;
    slot[p]       = make_float2(__expf(b0), __expf(l0));
    slot[p + 512] = make_float2(__expf(b1), __expf(l1));
}

__global__ __launch_bounds__(576)
void ctc_fused_kernel(const float* __restrict__ log_probs,
                      const int*   __restrict__ targets,
                      const int*   __restrict__ input_lengths,
                      const int*   __restrict__ target_lengths,
                      float*       __restrict__ losses,
                      unsigned*    __restrict__ counter,
                      float*       __restrict__ out)
{
    __shared__ float2 ring[4 * 1024];                 // 4-chunk ring, 32 KB
    const int  b    = blockIdx.x;
    const int  tid  = threadIdx.x;
    const int  len  = input_lengths[b];
    const bool prod = (tid < 512);

    // producer-persistent
    const int j    = tid & 31;
    const int trow = (tid & 511) >> 5;
    int lab = 0;
    // scanner-persistent
    const int l  = tid - 512;                         // lane in scanner wave
    const int jl = tid & 31;
    ScanSt st = {0.f, 0.f, 0};
    float skipw = 0.f;
    bool  is16  = false;

    if (prod) {
        lab = (j < S_DIM) ? targets[b * S_DIM + j] : 0;
        stage_chunk(0, b, trow, lab, tid, log_probs, ring);
        stage_chunk(1, b, trow, lab, tid, log_probs, ring);
        stage_chunk(2, b, trow, lab, tid, log_probs, ring);
    } else {
        is16 = (l == 16);
        bool allow = (l == 0);
        if (l >= 1 && l < S_DIM)
            allow = (targets[b * S_DIM + l] != targets[b * S_DIM + l - 1]);
        skipw = allow ? 1.f : 0.f;
    }
    __syncthreads();

    for (int c = 0; c < 16; ++c) {
        if (prod) {
            if (c < 13) stage_chunk(c + 3, b, trow, lab, tid, log_probs, ring);
        } else {
            const float2* ringc = ring + (size_t)(c & 3) * 1024;
            if (c == 0)                   consume_chunk<0>(ringc, c, len, jl, is16, skipw, l, st);
            else if ((c + 1) * 32 <= len) consume_chunk<1>(ringc, c, len, jl, is16, skipw, l, st);
            else if (c * 32 < len)        consume_chunk<2>(ringc, c, len, jl, is16, skipw, l, st);
        }
        __syncthreads();                              // uniform: every wave, every c
    }

    if (!prod) {
        float pB = __shfl(st.p0, 30);                 // alpha[2*tl]   (pos 60)
        float pL = __shfl(st.p1, 29);                 // alpha[2*tl-1] (pos 59)
        int   tl = target_lengths[b];
        float loss = 0.f;
        if (l == 0) {
            loss = -LN2 * (__builtin_amdgcn_logf(pB + pL) - (float)st.E);
            if (!(loss < 1e29f)) loss = 0.f;          // zero_infinity (inf/NaN)
            loss /= (float)tl;
        }

        // in-kernel tail (proven in R6/R8/R11): lane0 publishes, last block
        // reduces lane-parallel. Replaces round 4's second kernel + launch gap.
        unsigned old = 0;
        if (l == 0) {
            losses[b] = loss;
            __threadfence();                          // release per-block loss
            old = atomicAdd(counter, 1u);             // device scope
        }
        old = __shfl(old, 0);
        if (old == 63u) {                             // last block, lane-parallel
            __threadfence();                          // acquire
            float v = ((volatile const float*)losses)[l];
#pragma unroll
            for (int off = 32; off >= 1; off >>= 1)
                v += __shfl_xor(v, off);
            if (l == 0) out[0] = v * (1.f / (float)B_DIM);
        }
    }
}

extern "C" void kernel_launch(void* const* d_in, const int* in_sizes, int n_in,
                              void* d_out, int out_size, void* d_ws, size_t ws_size,
                              hipStream_t stream)
{
    const float* log_probs      = (const float*)d_in[0];
    const int*   targets        = (const int*)  d_in[1];
    const int*   input_lengths  = (const int*)  d_in[2];
    const int*   target_lengths = (const int*)  d_in[3];
    float*       out            = (float*)d_out;
    float*       losses         = (float*)d_ws;                    // 64 floats
    unsigned*    counter        = (unsigned*)((char*)d_ws + 256);  // own cache line

    hipMemsetAsync(counter, 0, sizeof(unsigned), stream);          // capturable
    hipLaunchKernelGGL(ctc_fused_kernel, dim3(B_DIM), dim3(576), 0, stream,
                       log_probs, targets, input_lengths, target_lengths,
                       losses, counter, out);
}